// Round 20
// baseline (552.969 us; speedup 1.0000x reference)
//
#include <hip/hip_runtime.h>

#define BB 256
#define TT 512
#define II 64
#define DD 512
#define OO 128
#define LN_EPS 1e-5f

__device__ __forceinline__ float fast_tanh(float x) {
    // tanh(x) = 1 - 2/(exp(2x)+1); exact saturation at +/-inf
    float e = __expf(2.0f * x);
    return 1.0f - 2.0f / (e + 1.0f);
}

// ---------------------------------------------------------------------------
// FUSED kernel: embed + recurrence + LN + output projection, one block per
// batch row (4 waves, 2 d per thread). The embed GEMM work (128 fma/thread/
// step) is independent of the recurrence, so it is computed ONE STEP AHEAD
// inside the butterfly region: the compiler interleaves the fma chain with
// the 6 dependent shfl waits (VALUBusy was only 21% — pure headroom).
//
// W_in rows (d2, d2+1) live in REGISTERS (32x float4, statically indexed
// under full unroll). x rows stream through a 2-slot LDS ping-pong staged
// 2 steps ahead by 16 threads (global->reg at t-1, reg->LDS at t, read at
// t+1 — each hop separated by the existing per-step barrier).
//
// Numerics: e = i-ascending fmaf chain + b_in + fast_tanh — bit-identical to
// the verified embed kernel. Recurrence/butterfly/exchange/epilogue text is
// byte-identical to the PASSING round-14 kernel. Output should bit-match.
// ---------------------------------------------------------------------------
__global__ __launch_bounds__(256)
void fused_kernel(const float* __restrict__ x,
                  const float* __restrict__ W_in,
                  const float* __restrict__ b_in,
                  const float* __restrict__ gamma,
                  const float* __restrict__ beta,
                  const float* __restrict__ W_out,
                  const float* __restrict__ b_out,
                  const float* __restrict__ cs,
                  float* __restrict__ out)
{
    const int b    = blockIdx.x;
    const int tid  = threadIdx.x;      // 0..255
    const int wave = tid >> 6;         // 0..3
    const int lane = tid & 63;
    const int d2   = tid << 1;         // this thread's d base (2 elements)

    __shared__ __align__(16) float4 xrow[2][16];   // x-row ping-pong (2 x 64 f32)
    __shared__ __align__(16) float red[2][4][2];
    __shared__ float h_lds[DD];

    // ---- one-time: W_in rows d2, d2+1 -> registers (statically indexed) ----
    float4 wA[16], wB[16];
    {
        const float* wrA = W_in + (size_t)d2 * II;
        const float* wrB = W_in + (size_t)(d2 + 1) * II;
        #pragma unroll
        for (int k = 0; k < 16; ++k) {
            wA[k] = *(const float4*)(wrA + k * 4);
            wB[k] = *(const float4*)(wrB + k * 4);
        }
    }
    const float2 bin = *(const float2*)(b_in + d2);
    const float2 g   = *(const float2*)(gamma + d2);
    const float2 bt  = *(const float2*)(beta  + d2);
    const float scale = 1.0f / (1.0f + __expf(-cs[0]));

    const float* xb = x + (size_t)b * TT * II;

    // ---- prologue: stage x rows 0,1; preload row 2 into regs ----
    float4 xg;
    if (tid < 16) {
        xrow[0][tid] = *(const float4*)(xb + (size_t)0 * II + tid * 4);
        xrow[1][tid] = *(const float4*)(xb + (size_t)1 * II + tid * 4);
        xg           = *(const float4*)(xb + (size_t)2 * II + tid * 4);
    }
    __syncthreads();

    // e_0 (embed math: i-ascending fmaf chain, +b_in, tanh — bit-identical)
    float2 ecur;
    {
        float ax = 0.0f, ay = 0.0f;
        #pragma unroll
        for (int k = 0; k < 16; ++k) {
            const float4 xv = xrow[0][k];
            ax = fmaf(xv.x, wA[k].x, ax); ax = fmaf(xv.y, wA[k].y, ax);
            ax = fmaf(xv.z, wA[k].z, ax); ax = fmaf(xv.w, wA[k].w, ax);
            ay = fmaf(xv.x, wB[k].x, ay); ay = fmaf(xv.y, wB[k].y, ay);
            ay = fmaf(xv.z, wB[k].z, ay); ay = fmaf(xv.w, wB[k].w, ay);
        }
        ecur.x = fast_tanh(ax + bin.x);
        ecur.y = fast_tanh(ay + bin.y);
    }
    __syncthreads();   // protect xrow[0] readers from step-0's overwrite

    float2 sp, hp;
    sp.x = sp.y = 0.0f; hp = sp;

    #pragma unroll 1
    for (int t = 0; t < TT; ++t) {
        // -- recurrence step (text identical to round-14 passing kernel) --
        float2 s;
        s.x = fast_tanh(ecur.x + scale * sp.x + hp.x);
        s.y = fast_tanh(ecur.y + scale * sp.y + hp.y);

        float r0 = s.x + s.y;
        float r1 = s.x * s.x + s.y * s.y;
        #pragma unroll
        for (int m = 32; m >= 1; m >>= 1) {
            r0 += __shfl_xor(r0, m, 64);
            r1 += __shfl_xor(r1, m, 64);
        }

        // -- e_{t+1}: independent of the recurrence; interleaves with the
        //    shfl waits above. Reads xrow[(t+1)&1] = row t+1 (staged one
        //    barrier ago; different slot from this step's write below). --
        float2 en;
        {
            float ax = 0.0f, ay = 0.0f;
            const float4* xr = xrow[(t + 1) & 1];
            #pragma unroll
            for (int k = 0; k < 16; ++k) {
                const float4 xv = xr[k];
                ax = fmaf(xv.x, wA[k].x, ax); ax = fmaf(xv.y, wA[k].y, ax);
                ax = fmaf(xv.z, wA[k].z, ax); ax = fmaf(xv.w, wA[k].w, ax);
                ay = fmaf(xv.x, wB[k].x, ay); ay = fmaf(xv.y, wB[k].y, ay);
                ay = fmaf(xv.z, wB[k].z, ay); ay = fmaf(xv.w, wB[k].w, ay);
            }
            en.x = fast_tanh(ax + bin.x);
            en.y = fast_tanh(ay + bin.y);
        }

        const int p = t & 1;
        if (lane == 0) { red[p][wave][0] = r0; red[p][wave][1] = r1; }

        // -- x staging: write row t+2 (reg->LDS, slot t&1: its readers ran
        //    at step t-1 before that step's barrier); issue load row t+3 --
        if (tid < 16) {
            xrow[t & 1][tid] = xg;
            const int tld = (t + 3 < TT) ? (t + 3) : (TT - 1);
            xg = *(const float4*)(xb + (size_t)tld * II + tid * 4);
        }
        __syncthreads();

        const float4 ra = *(const float4*)&red[p][0][0];   // waves 0,1
        const float4 rb = *(const float4*)&red[p][2][0];   // waves 2,3
        const float sum   = (ra.x + ra.z) + (rb.x + rb.z);
        const float sumsq = (ra.y + ra.w) + (rb.y + rb.w);

        const float mu   = sum * (1.0f / DD);
        const float var  = sumsq * (1.0f / DD) - mu * mu;
        const float rstd = rsqrtf(var + LN_EPS);

        hp.x = (s.x - mu) * rstd * g.x + bt.x;
        hp.y = (s.y - mu) * rstd * g.y + bt.y;
        sp = s;
        ecur = en;
    }

    // -- epilogue: logits[b, o] = h . W_out[o, :] + b_out[o] (round-14 text) --
    h_lds[d2]     = hp.x;
    h_lds[d2 + 1] = hp.y;
    __syncthreads();

    const int dbase = lane * 8;
    float hreg[8];
    #pragma unroll
    for (int k = 0; k < 8; ++k) hreg[k] = h_lds[dbase + k];

    for (int oo = 0; oo < 32; ++oo) {
        const int o = wave * 32 + oo;
        const float* wo = W_out + (size_t)o * DD + dbase;
        float pacc = 0.f;
        #pragma unroll
        for (int k = 0; k < 8; ++k) pacc = fmaf(wo[k], hreg[k], pacc);
        #pragma unroll
        for (int m = 32; m >= 1; m >>= 1) pacc += __shfl_xor(pacc, m, 64);
        if (lane == 0) out[(size_t)b * OO + o] = pacc + b_out[o];
    }
}

extern "C" void kernel_launch(void* const* d_in, const int* in_sizes, int n_in,
                              void* d_out, int out_size, void* d_ws, size_t ws_size,
                              hipStream_t stream) {
    const float* x      = (const float*)d_in[0];
    const float* W_in   = (const float*)d_in[1];
    const float* b_in   = (const float*)d_in[2];
    const float* gamma  = (const float*)d_in[3];
    const float* beta   = (const float*)d_in[4];
    const float* W_out  = (const float*)d_in[5];
    const float* b_out  = (const float*)d_in[6];
    const float* cs     = (const float*)d_in[7];
    float* out = (float*)d_out;

    (void)d_ws; (void)ws_size;   // fused: no E workspace, no chunking, no state

    fused_kernel<<<BB, 256, 0, stream>>>(x, W_in, b_in, gamma, beta,
                                         W_out, b_out, cs, out);
}